// Round 12
// baseline (110.464 us; speedup 1.0000x reference)
//
#include <hip/hip_runtime.h>
#include <math.h>

// ---------------------------------------------------------------------------
// Fully-fused SAFM, one launch. R12: SMALLER BLOCKS for occupancy/overlap.
// R6-R11 post-mortem: kernel pinned at ~44us across 4 different bodies with
// VALUBusy ~26% / occupancy ~25% -> 74% stalled, barrier-lockstep + too few
// independent blocks per CU (8). Now: block = 128 threads (2 waves), tile =
// 8w x 2h pixels (4 ebs), grid 4096 (16 blocks/CU of work), LDS 12.1 KB.
// Same math as R11 (E recomputed, never stored; all f32).
//
// Phases: P1 {pool p1 patch 6x8 + s0 dwconv -> s0s}
//         P2 {k dwconv -> reg, v dwconv (p2=max4(p1s) on the fly) -> vsh}
//         P3 {denom_j via 32 exps; store (kl,nm) + q*rd}
//         P4 {recompute exps row-wise, accumulate qkv -> qkvs (overlay p1s)}
//         P5 {1x1 conv + exact GELU + mul x}
// No launch_bounds min-waves (R5/R6: it forces spills).
// ---------------------------------------------------------------------------

__global__ __launch_bounds__(128) void fused_safm(
    const float* __restrict__ x,
    const float* __restrict__ w0, const float* __restrict__ b0,
    const float* __restrict__ w1, const float* __restrict__ b1,
    const float* __restrict__ w2, const float* __restrict__ b2,
    const float* __restrict__ wa, const float* __restrict__ ba,
    float* __restrict__ out) {
  int bid = blockIdx.x;
  int twq = bid & 15, th = (bid >> 4) & 63, b = bid >> 10;
  int t = threadIdx.x;
  int h4 = th >> 1;

  __shared__ __align__(16) float regAB[1664]; // p1s (P1-P2) / qkvs (P4-P5)
  __shared__ __align__(16) float s0s[528];    // [p][c] stride 33 (16 px)
  __shared__ __align__(16) float klns[256];   // (eb*32+j)*2: {kl, nm}
  __shared__ __align__(16) float qds[512];    // (eb*32+j)*4: q[px]*rd
  __shared__ __align__(16) float vsh[144];    // [eb][i] stride 36 (4 ebs)
  float* p1s  = regAB;                        // [c][6r][8w] c-stride 52
  float* qkvs = regAB;                        // [p][i] stride 36 (16 px)

  // ---- P1a: pool p1 patch rows 2h4-2..+3, cols 4twq-2..+5 (zero OOB) ----
  {
    const float* xb = x + ((size_t)(b * 32) << 14);
#pragma unroll
    for (int k = 0; k < 3; ++k) {
      int idx = t + k * 128;                  // 384 units = 32c * 6r * 2seg
      int c = idx / 12, rem = idx % 12;
      int r = rem >> 1, s = rem & 1;
      int pr = 2 * h4 - 2 + r;
      int pc0 = 4 * twq - 2 + 4 * s;
      float m0 = 0.f, m1 = 0.f, m2 = 0.f, m3 = 0.f;
      if ((unsigned)pr < 64u) {
        const float* xp = xb + ((size_t)c << 14) + (2 * pr) * 128;
        if (pc0 >= 0 && pc0 + 3 < 64) {       // interior fast path
          const float* q = xp + 2 * pc0;
          float4 a0 = *(const float4*)q;
          float4 a1 = *(const float4*)(q + 4);
          float4 c0 = *(const float4*)(q + 128);
          float4 c1 = *(const float4*)(q + 132);
          m0 = fmaxf(fmaxf(a0.x, a0.y), fmaxf(c0.x, c0.y));
          m1 = fmaxf(fmaxf(a0.z, a0.w), fmaxf(c0.z, c0.w));
          m2 = fmaxf(fmaxf(a1.x, a1.y), fmaxf(c1.x, c1.y));
          m3 = fmaxf(fmaxf(a1.z, a1.w), fmaxf(c1.z, c1.w));
        } else {                              // edge slow path
          float mm[4] = {0.f, 0.f, 0.f, 0.f};
#pragma unroll
          for (int m_ = 0; m_ < 4; ++m_) {
            int pc = pc0 + m_;
            if ((unsigned)pc < 64u) {
              const float* q = xp + 2 * pc;
              float2 r0 = *(const float2*)q;
              float2 r1 = *(const float2*)(q + 128);
              mm[m_] = fmaxf(fmaxf(r0.x, r0.y), fmaxf(r1.x, r1.y));
            }
          }
          m0 = mm[0]; m1 = mm[1]; m2 = mm[2]; m3 = mm[3];
        }
      }
      *(float4*)(p1s + c * 52 + r * 8 + 4 * s) = make_float4(m0, m1, m2, m3);
    }
  }
  // ---- P1b: s0 dwconv from global -> s0s (4 px/thread) ----
  {
    int c = t >> 2, gg = t & 3;
    int hh = gg >> 1, wb = (gg & 1) * 4;
    const float* xp = x + ((size_t)(b * 32 + c) << 14);
    const float* wc = w0 + c * 9;
    float wv[9];
#pragma unroll
    for (int q = 0; q < 9; ++q) wv[q] = wc[q];
    float bz = b0[c];
    float a0 = bz, a1 = bz, a2 = bz, a3 = bz;
    int cbase = 8 * twq + wb;
#pragma unroll
    for (int dr = -1; dr <= 1; ++dr) {
      int row = 2 * th + hh + dr;
      if ((unsigned)row >= 128u) continue;
      const float* rp = xp + row * 128 + cbase;
      float cm1 = (cbase > 0)       ? rp[-1] : 0.f;
      float4 c03 = *(const float4*)rp;
      float c4  = (cbase + 4 < 128) ? rp[4]  : 0.f;
      float wA = wv[(dr + 1) * 3], wB = wv[(dr + 1) * 3 + 1], wC = wv[(dr + 1) * 3 + 2];
      a0 = fmaf(wA, cm1,   fmaf(wB, c03.x, fmaf(wC, c03.y, a0)));
      a1 = fmaf(wA, c03.x, fmaf(wB, c03.y, fmaf(wC, c03.z, a1)));
      a2 = fmaf(wA, c03.y, fmaf(wB, c03.z, fmaf(wC, c03.w, a2)));
      a3 = fmaf(wA, c03.z, fmaf(wB, c03.w, fmaf(wC, c4,    a3)));
    }
    int pb = hh * 8 + wb;
    s0s[(pb)     * 33 + c] = a0;
    s0s[(pb + 1) * 33 + c] = a1;
    s0s[(pb + 2) * 33 + c] = a2;
    s0s[(pb + 3) * 33 + c] = a3;
  }
  __syncthreads();

  // ---- P2: k dwconv -> register; v dwconv (p2 = max4(p1s) on the fly) ----
  int ebT = t >> 5, jT = t & 31;              // eb 0..3, j 0..31
  float kreg;
  {
    const float* wc = w1 + jT * 9;
    const float* Pk = p1s + jT * 52 + ((th & 1) + 1) * 8 + (ebT + 1);
    float acc = b1[jT];
    acc = fmaf(wc[0], Pk[0],  fmaf(wc[1], Pk[1],  fmaf(wc[2], Pk[2],  acc)));
    acc = fmaf(wc[3], Pk[8],  fmaf(wc[4], Pk[9],  fmaf(wc[5], Pk[10], acc)));
    acc = fmaf(wc[6], Pk[16], fmaf(wc[7], Pk[17], fmaf(wc[8], Pk[18], acc)));
    kreg = acc;
  }
  {
    const float* wc = w2 + jT * 9;
    const float* P = p1s + jT * 52 + 2 * (ebT >> 1);
    float acc = b2[jT];
#pragma unroll
    for (int hq = 0; hq < 3; ++hq) {
      const float* Pr = P + hq * 16;          // 2 p1-rows per p2-row
#pragma unroll
      for (int wq = 0; wq < 3; ++wq) {
        float2 u0 = *(const float2*)(Pr + 2 * wq);
        float2 u1 = *(const float2*)(Pr + 2 * wq + 8);
        float p2v = fmaxf(fmaxf(u0.x, u0.y), fmaxf(u1.x, u1.y));
        acc = fmaf(wc[hq * 3 + wq], p2v, acc);
      }
    }
    vsh[ebT * 36 + jT] = acc;
  }
  __syncthreads();

  // ---- P3 (column pass): denom_j; store {kl_j,nm_j} and q[px]*rd ----
  {
    const float* vb = vsh + ebT * 36;
    const float4* v4 = (const float4*)vb;
    float4 q0 = v4[0];
    float vmax = fmaxf(fmaxf(q0.x, q0.y), fmaxf(q0.z, q0.w));
    float vmin = fminf(fminf(q0.x, q0.y), fminf(q0.z, q0.w));
#pragma unroll
    for (int iq = 1; iq < 8; ++iq) {
      float4 q_ = v4[iq];
      vmax = fmaxf(vmax, fmaxf(fmaxf(q_.x, q_.y), fmaxf(q_.z, q_.w)));
      vmin = fminf(vmin, fminf(fminf(q_.x, q_.y), fminf(q_.z, q_.w)));
    }
    const float L2E = 1.4426950408889634f;
    float m  = (kreg >= 0.f) ? kreg * vmax : kreg * vmin;   // max_i v_i*k_j
    float kl = kreg * L2E;
    float nm = -m * L2E;
    float d0 = 0.f, d1 = 0.f;
#pragma unroll
    for (int ip = 0; ip < 16; ++ip) {
      float2 vp = *(const float2*)(vb + 2 * ip);
      d0 += __builtin_amdgcn_exp2f(fmaf(vp.x, kl, nm));
      d1 += __builtin_amdgcn_exp2f(fmaf(vp.y, kl, nm));
    }
    float rd = __fdividef(1.f, d0 + d1);
    *(float2*)(klns + (ebT * 32 + jT) * 2) = make_float2(kl, nm);
    float4 qv;                  // pixel slots: {2eb, 2eb+1, 8+2eb, 9+2eb}
    qv.x = s0s[(2 * ebT)     * 33 + jT] * rd;
    qv.y = s0s[(2 * ebT + 1) * 33 + jT] * rd;
    qv.z = s0s[(2 * ebT + 8) * 33 + jT] * rd;
    qv.w = s0s[(2 * ebT + 9) * 33 + jT] * rd;
    *(float4*)(qds + (ebT * 32 + jT) * 4) = qv;
  }
  __syncthreads();

  // ---- P4 (row pass): qkv[i][px] = sum_j exp(v_i*kl_j+nm_j) * qd[j][px] ----
  {
    int i = t & 31, eb = t >> 5;
    float vi = vsh[eb * 36 + i];
    const float* klp = klns + eb * 64;
    const float* qdp = qds + eb * 128;
    float a0 = 0.f, a1 = 0.f, a2 = 0.f, a3 = 0.f;
#pragma unroll
    for (int jw = 0; jw < 8; ++jw) {
      float4 k01 = *(const float4*)(klp + jw * 8);       // {kl,nm}x2 broadcast
      float4 k23 = *(const float4*)(klp + jw * 8 + 4);
      float4 qd0 = *(const float4*)(qdp + jw * 16);
      float4 qd1 = *(const float4*)(qdp + jw * 16 + 4);
      float4 qd2 = *(const float4*)(qdp + jw * 16 + 8);
      float4 qd3 = *(const float4*)(qdp + jw * 16 + 12);
      float e;
      e = __builtin_amdgcn_exp2f(fmaf(vi, k01.x, k01.y));
      a0 = fmaf(e, qd0.x, a0); a1 = fmaf(e, qd0.y, a1);
      a2 = fmaf(e, qd0.z, a2); a3 = fmaf(e, qd0.w, a3);
      e = __builtin_amdgcn_exp2f(fmaf(vi, k01.z, k01.w));
      a0 = fmaf(e, qd1.x, a0); a1 = fmaf(e, qd1.y, a1);
      a2 = fmaf(e, qd1.z, a2); a3 = fmaf(e, qd1.w, a3);
      e = __builtin_amdgcn_exp2f(fmaf(vi, k23.x, k23.y));
      a0 = fmaf(e, qd2.x, a0); a1 = fmaf(e, qd2.y, a1);
      a2 = fmaf(e, qd2.z, a2); a3 = fmaf(e, qd2.w, a3);
      e = __builtin_amdgcn_exp2f(fmaf(vi, k23.z, k23.w));
      a0 = fmaf(e, qd3.x, a0); a1 = fmaf(e, qd3.y, a1);
      a2 = fmaf(e, qd3.z, a2); a3 = fmaf(e, qd3.w, a3);
    }
    qkvs[(2 * eb)     * 36 + i] = a0;
    qkvs[(2 * eb + 1) * 36 + i] = a1;
    qkvs[(2 * eb + 8) * 36 + i] = a2;
    qkvs[(2 * eb + 9) * 36 + i] = a3;
  }
  __syncthreads();

  // ---- P5: 1x1 conv + exact GELU + mul x (4 outputs/thread) ----
  {
    int o = t >> 2, g = t & 3;
    int hh = g >> 1, wb = (g & 1) * 4;
    const float* wo = wa + o * 32;
    const float* qA = qkvs + (hh * 8 + wb)     * 36;
    const float* qB = qkvs + (hh * 8 + wb + 1) * 36;
    const float* qC = qkvs + (hh * 8 + wb + 2) * 36;
    const float* qD = qkvs + (hh * 8 + wb + 3) * 36;
    float bz = ba[o];
    float y0 = bz, y1 = bz, y2 = bz, y3 = bz;
#pragma unroll
    for (int m = 0; m < 8; ++m) {
      float4 fA = *(const float4*)(qA + 4 * m);
      float4 fB = *(const float4*)(qB + 4 * m);
      float4 fC = *(const float4*)(qC + 4 * m);
      float4 fD = *(const float4*)(qD + 4 * m);
      float wv0 = wo[4 * m], wv1 = wo[4 * m + 1], wv2 = wo[4 * m + 2], wv3 = wo[4 * m + 3];
      y0 = fmaf(wv0, fA.x, fmaf(wv1, fA.y, fmaf(wv2, fA.z, fmaf(wv3, fA.w, y0))));
      y1 = fmaf(wv0, fB.x, fmaf(wv1, fB.y, fmaf(wv2, fB.z, fmaf(wv3, fB.w, y1))));
      y2 = fmaf(wv0, fC.x, fmaf(wv1, fC.y, fmaf(wv2, fC.z, fmaf(wv3, fC.w, y2))));
      y3 = fmaf(wv0, fD.x, fmaf(wv1, fD.y, fmaf(wv2, fD.z, fmaf(wv3, fD.w, y3))));
    }
    const float RS2 = 0.70710678118654752f;
    float g0 = 0.5f * y0 * (1.f + erff(y0 * RS2));
    float g1 = 0.5f * y1 * (1.f + erff(y1 * RS2));
    float g2 = 0.5f * y2 * (1.f + erff(y2 * RS2));
    float g3 = 0.5f * y3 * (1.f + erff(y3 * RS2));
    size_t ob = (((size_t)(b * 32 + o) * 128) + (2 * th + hh)) * 128 + 8 * twq + wb;
    float4 xv = *(const float4*)(x + ob);
    float4 r;
    r.x = g0 * xv.x; r.y = g1 * xv.y; r.z = g2 * xv.z; r.w = g3 * xv.w;
    *(float4*)(out + ob) = r;
  }
}

// ---------------------------------------------------------------------------
extern "C" void kernel_launch(void* const* d_in, const int* in_sizes, int n_in,
                              void* d_out, int out_size, void* d_ws, size_t ws_size,
                              hipStream_t stream) {
  const float* x  = (const float*)d_in[0];
  const float* w0 = (const float*)d_in[1];
  const float* b0 = (const float*)d_in[2];
  const float* w1 = (const float*)d_in[3];
  const float* b1 = (const float*)d_in[4];
  const float* w2 = (const float*)d_in[5];
  const float* b2 = (const float*)d_in[6];
  const float* wa = (const float*)d_in[7];
  const float* ba = (const float*)d_in[8];
  float* out = (float*)d_out;

  fused_safm<<<4096, 128, 0, stream>>>(x, w0, b0, w1, b1, w2, b2, wa, ba, out);
}